// Round 1
// baseline (632.126 us; speedup 1.0000x reference)
//
#include <hip/hip_runtime.h>

#define NN 50000
#define NE 800000
#define C 128
#define OUTC 64
#define BN_EPS 1e-5f

// ---------------- CSR build ----------------

__global__ __launch_bounds__(256) void hist_kernel(const int* __restrict__ dstp, int* __restrict__ cnt) {
    int e = blockIdx.x * 256 + threadIdx.x;
    if (e < NE) atomicAdd(&cnt[dstp[e]], 1);
}

__global__ __launch_bounds__(1024) void scan_kernel(const int* __restrict__ cnt, int* __restrict__ rowptr,
                                                    int* __restrict__ wpos, float* __restrict__ dinv) {
    __shared__ int lds[1024];
    __shared__ int carry;
    int tid = threadIdx.x;
    if (tid == 0) carry = 0;
    __syncthreads();
    for (int base = 0; base < NN; base += 1024) {
        int i = base + tid;
        int v = (i < NN) ? cnt[i] : 0;
        lds[tid] = v;
        __syncthreads();
        for (int off = 1; off < 1024; off <<= 1) {
            int x = (tid >= off) ? lds[tid - off] : 0;
            __syncthreads();
            lds[tid] += x;
            __syncthreads();
        }
        int excl = lds[tid] - v;
        if (i < NN) {
            int rp = carry + excl;
            rowptr[i] = rp;
            wpos[i] = rp;
            dinv[i] = rsqrtf((float)(v + 1));   // +1 self-loop
        }
        __syncthreads();
        if (tid == 1023) carry += lds[1023];
        __syncthreads();
    }
    if (tid == 0) rowptr[NN] = carry;
}

__global__ __launch_bounds__(256) void fill_kernel(const int* __restrict__ srcp, const int* __restrict__ dstp,
                                                   int* __restrict__ wpos, int* __restrict__ col) {
    int e = blockIdx.x * 256 + threadIdx.x;
    if (e < NE) {
        int d = dstp[e];
        int p = atomicAdd(&wpos[d], 1);
        col[p] = srcp[e];
    }
}

// Combine Wmu|Wls into one [128][128] and bmu|bls into one [128]
__global__ __launch_bounds__(256) void prep_kernel(const float* __restrict__ Wmu, const float* __restrict__ Wls,
                                                   const float* __restrict__ bmu, const float* __restrict__ bls,
                                                   float* __restrict__ Wcomb, float* __restrict__ biasc) {
    int tid = blockIdx.x * 256 + threadIdx.x;
    if (tid < 128 * 128) {
        int k = tid >> 7, c = tid & 127;
        Wcomb[tid] = (c < 64) ? Wmu[k * 64 + c] : Wls[k * 64 + (c - 64)];
    }
    if (tid < 128) biasc[tid] = (tid < 64) ? bmu[tid] : bls[tid - 64];
}

// ---------------- GEMM: [N x 128] @ [128 x 128], f32 vector ALU ----------------
// TRANS: apply per-channel scale/shift + relu to A on load (fused BN+ReLU of previous layer)
// SPLIT: write cols 0..63 to out (+bias), 64..127 to out2 (+bias), row stride 64

template<bool TRANS, bool SPLIT>
__global__ __launch_bounds__(256) void gemm_kernel(
    const float* __restrict__ A, const float* __restrict__ W,
    const float* __restrict__ scale, const float* __restrict__ shift,
    const float* __restrict__ bias,
    float* __restrict__ out, float* __restrict__ out2)
{
    __shared__ float Ws[64][128];    // 32 KB (one k-half of W)
    __shared__ float xT[128][36];    // 18 KB (transposed 32-row tile, padded)
    int tid = threadIdx.x;
    int row0 = blockIdx.x * 32;

    for (int i = 0; i < 16; ++i) {          // stage 32x128 input tile, transposed
        int idx = tid + i * 256;
        int r = idx >> 7, k = idx & 127;
        int gr = row0 + r;
        float v = (gr < NN) ? A[gr * C + k] : 0.f;
        if (TRANS) v = fmaxf(fmaf(v, scale[k], shift[k]), 0.f);
        xT[k][r] = v;
    }

    float acc[4][4] = {};
    int cg = (tid & 31) * 4;   // output col base
    int rg = (tid >> 5) * 4;   // local row base

    for (int kh = 0; kh < 2; ++kh) {
        __syncthreads();
        for (int i = 0; i < 8; ++i) {       // stage W k-half
            int fi = tid + i * 256;         // float4 index 0..2047
            int k = fi >> 5;
            int c4 = (fi & 31) * 4;
            *(float4*)&Ws[k][c4] = *(const float4*)&W[(kh * 64 + k) * C + c4];
        }
        __syncthreads();
        #pragma unroll 8
        for (int k = 0; k < 64; ++k) {
            float4 a = *(const float4*)&xT[kh * 64 + k][rg];
            float4 b = *(const float4*)&Ws[k][cg];
            acc[0][0] = fmaf(a.x, b.x, acc[0][0]); acc[0][1] = fmaf(a.x, b.y, acc[0][1]);
            acc[0][2] = fmaf(a.x, b.z, acc[0][2]); acc[0][3] = fmaf(a.x, b.w, acc[0][3]);
            acc[1][0] = fmaf(a.y, b.x, acc[1][0]); acc[1][1] = fmaf(a.y, b.y, acc[1][1]);
            acc[1][2] = fmaf(a.y, b.z, acc[1][2]); acc[1][3] = fmaf(a.y, b.w, acc[1][3]);
            acc[2][0] = fmaf(a.z, b.x, acc[2][0]); acc[2][1] = fmaf(a.z, b.y, acc[2][1]);
            acc[2][2] = fmaf(a.z, b.z, acc[2][2]); acc[2][3] = fmaf(a.z, b.w, acc[2][3]);
            acc[3][0] = fmaf(a.w, b.x, acc[3][0]); acc[3][1] = fmaf(a.w, b.y, acc[3][1]);
            acc[3][2] = fmaf(a.w, b.z, acc[3][2]); acc[3][3] = fmaf(a.w, b.w, acc[3][3]);
        }
    }

    #pragma unroll
    for (int i = 0; i < 4; ++i) {
        int row = row0 + rg + i;
        if (row < NN) {
            if (!SPLIT) {
                float4 o = make_float4(acc[i][0], acc[i][1], acc[i][2], acc[i][3]);
                *(float4*)&out[row * C + cg] = o;
            } else {
                float* dst = (cg < 64) ? out : out2;
                int cc = cg & 63;
                float4 o = make_float4(acc[i][0] + bias[cg], acc[i][1] + bias[cg + 1],
                                       acc[i][2] + bias[cg + 2], acc[i][3] + bias[cg + 3]);
                *(float4*)&dst[row * 64 + cc] = o;
            }
        }
    }
}

// ---------------- Pull aggregation: out[i] = dinv[i]*(sum_e dinv[s]*f(t[s]) + dinv[i]*f(t[i])) ----------------
// TRANS: f(v) = relu(v*scale[c]+shift[c]) (fused BN+ReLU of previous layer), else identity

template<bool TRANS>
__global__ __launch_bounds__(256) void agg_kernel(
    const float* __restrict__ t, const int* __restrict__ rowptr, const int* __restrict__ col,
    const float* __restrict__ dinv, const float* __restrict__ scale, const float* __restrict__ shift,
    float* __restrict__ outb)
{
    int wave = threadIdx.x >> 6;
    int lane = threadIdx.x & 63;
    int row = blockIdx.x * 4 + wave;
    if (row >= NN) return;
    int c = lane * 2;
    float sc0 = 1.f, sc1 = 1.f, sh0 = 0.f, sh1 = 0.f;
    if (TRANS) { sc0 = scale[c]; sc1 = scale[c + 1]; sh0 = shift[c]; sh1 = shift[c + 1]; }
    float di = dinv[row];
    int e0 = rowptr[row], e1 = rowptr[row + 1];
    float a0 = 0.f, a1 = 0.f;
    int e = e0;
    for (; e + 1 < e1; e += 2) {     // unroll-2 to overlap the idx->gather chains
        int s0 = col[e], s1 = col[e + 1];
        float dv0 = dinv[s0], dv1 = dinv[s1];
        float2 v0 = *(const float2*)&t[s0 * C + c];
        float2 v1 = *(const float2*)&t[s1 * C + c];
        if (TRANS) {
            v0.x = fmaxf(fmaf(v0.x, sc0, sh0), 0.f); v0.y = fmaxf(fmaf(v0.y, sc1, sh1), 0.f);
            v1.x = fmaxf(fmaf(v1.x, sc0, sh0), 0.f); v1.y = fmaxf(fmaf(v1.y, sc1, sh1), 0.f);
        }
        a0 = fmaf(dv0, v0.x, a0); a1 = fmaf(dv0, v0.y, a1);
        a0 = fmaf(dv1, v1.x, a0); a1 = fmaf(dv1, v1.y, a1);
    }
    if (e < e1) {
        int s0 = col[e];
        float dv0 = dinv[s0];
        float2 v0 = *(const float2*)&t[s0 * C + c];
        if (TRANS) { v0.x = fmaxf(fmaf(v0.x, sc0, sh0), 0.f); v0.y = fmaxf(fmaf(v0.y, sc1, sh1), 0.f); }
        a0 = fmaf(dv0, v0.x, a0); a1 = fmaf(dv0, v0.y, a1);
    }
    {   // self-loop
        float2 v = *(const float2*)&t[row * C + c];
        if (TRANS) { v.x = fmaxf(fmaf(v.x, sc0, sh0), 0.f); v.y = fmaxf(fmaf(v.y, sc1, sh1), 0.f); }
        a0 = fmaf(di, v.x, a0); a1 = fmaf(di, v.y, a1);
    }
    *(float2*)&outb[row * C + c] = make_float2(di * a0, di * a1);
}

// ---------------- BatchNorm stats ----------------

__global__ __launch_bounds__(256) void bnstats_kernel(const float* __restrict__ h, float* __restrict__ sums) {
    int c = threadIdx.x & 127;
    int hh = threadIdx.x >> 7;
    float s = 0.f, sq = 0.f;
    for (int r = blockIdx.x * 2 + hh; r < NN; r += gridDim.x * 2) {
        float v = h[r * C + c];
        s += v; sq = fmaf(v, v, sq);
    }
    __shared__ float ls[256], lq[256];
    ls[threadIdx.x] = s; lq[threadIdx.x] = sq;
    __syncthreads();
    if (hh == 0) {
        atomicAdd(&sums[c], s + ls[c + 128]);
        atomicAdd(&sums[128 + c], sq + lq[c + 128]);
    }
}

__global__ __launch_bounds__(128) void bnfin_kernel(const float* __restrict__ sums,
                                                    const float* __restrict__ gamma, const float* __restrict__ beta,
                                                    float* __restrict__ scale, float* __restrict__ shift) {
    int c = threadIdx.x;
    float invn = 1.f / (float)NN;
    float mean = sums[c] * invn;
    float var = sums[128 + c] * invn - mean * mean;
    float s = gamma[c] * rsqrtf(var + BN_EPS);
    scale[c] = s;
    shift[c] = fmaf(-mean, s, beta[c]);
}

// ---------------- launch ----------------

extern "C" void kernel_launch(void* const* d_in, const int* in_sizes, int n_in,
                              void* d_out, int out_size, void* d_ws, size_t ws_size,
                              hipStream_t stream) {
    (void)in_sizes; (void)n_in; (void)out_size; (void)ws_size;
    const float* x      = (const float*)d_in[0];
    const int*   ei     = (const int*)d_in[1];
    const float* W1     = (const float*)d_in[2];
    // d_in[3] = b1: cancelled exactly by BN mean-subtraction
    const float* gamma1 = (const float*)d_in[4];
    const float* beta1  = (const float*)d_in[5];
    const float* W2     = (const float*)d_in[6];
    // d_in[7] = b2: cancelled exactly by BN
    const float* gamma2 = (const float*)d_in[8];
    const float* beta2  = (const float*)d_in[9];
    const float* Wmu    = (const float*)d_in[10];
    const float* bmu    = (const float*)d_in[11];
    const float* Wls    = (const float*)d_in[12];
    const float* bls    = (const float*)d_in[13];

    float* outmu = (float*)d_out;
    float* outls = outmu + (size_t)NN * OUTC;

    char* w = (char*)d_ws;
    size_t off = 0;
    auto alloc = [&](size_t bytes) { char* p = w + off; off = (off + bytes + 255) & ~(size_t)255; return p; };
    float* t      = (float*)alloc(sizeof(float) * NN * C);       // 25.6 MB
    float* aggb   = (float*)alloc(sizeof(float) * NN * C);       // 25.6 MB
    int*   cnt    = (int*)  alloc(sizeof(int) * NN);
    int*   rowptr = (int*)  alloc(sizeof(int) * (NN + 1));
    int*   wpos   = (int*)  alloc(sizeof(int) * NN);
    int*   col    = (int*)  alloc(sizeof(int) * NE);
    float* dinv   = (float*)alloc(sizeof(float) * NN);
    float* sums   = (float*)alloc(sizeof(float) * 512);          // [sumsA(256) | sumsB(256)]
    float* scale1 = (float*)alloc(512);
    float* shift1 = (float*)alloc(512);
    float* scale2 = (float*)alloc(512);
    float* shift2 = (float*)alloc(512);
    float* Wcomb  = (float*)alloc(sizeof(float) * C * C);
    float* biasc  = (float*)alloc(512);
    float* sumsA = sums; float* sumsB = sums + 256;

    const int* srcp = ei;
    const int* dstp = ei + NE;

    hipMemsetAsync(cnt, 0, sizeof(int) * NN, stream);
    hipMemsetAsync(sums, 0, sizeof(float) * 512, stream);

    hist_kernel<<<(NE + 255) / 256, 256, 0, stream>>>(dstp, cnt);
    scan_kernel<<<1, 1024, 0, stream>>>(cnt, rowptr, wpos, dinv);
    fill_kernel<<<(NE + 255) / 256, 256, 0, stream>>>(srcp, dstp, wpos, col);
    prep_kernel<<<64, 256, 0, stream>>>(Wmu, Wls, bmu, bls, Wcomb, biasc);

    const int GB = (NN + 31) / 32;
    const int AB = (NN + 3) / 4;

    // layer 1: t = x@W1 ; aggb = A_hat t ; BN1 stats
    gemm_kernel<false, false><<<GB, 256, 0, stream>>>(x, W1, nullptr, nullptr, nullptr, t, nullptr);
    agg_kernel<false><<<AB, 256, 0, stream>>>(t, rowptr, col, dinv, nullptr, nullptr, aggb);
    bnstats_kernel<<<400, 256, 0, stream>>>(aggb, sumsA);
    bnfin_kernel<<<1, 128, 0, stream>>>(sumsA, gamma1, beta1, scale1, shift1);

    // layer 2: t = relu(BN1(aggb))@W2 ; aggb = A_hat t ; BN2 stats
    gemm_kernel<true, false><<<GB, 256, 0, stream>>>(aggb, W2, scale1, shift1, nullptr, t, nullptr);
    agg_kernel<false><<<AB, 256, 0, stream>>>(t, rowptr, col, dinv, nullptr, nullptr, aggb);
    bnstats_kernel<<<400, 256, 0, stream>>>(aggb, sumsB);
    bnfin_kernel<<<1, 128, 0, stream>>>(sumsB, gamma2, beta2, scale2, shift2);

    // heads: t = A_hat relu(BN2(aggb)) ; [mu|ls] = t @ [Wmu|Wls] + [bmu|bls]
    agg_kernel<true><<<AB, 256, 0, stream>>>(aggb, rowptr, col, dinv, scale2, shift2, t);
    gemm_kernel<false, true><<<GB, 256, 0, stream>>>(t, Wcomb, nullptr, nullptr, biasc, outmu, outls);
}

// Round 2
// 513.426 us; speedup vs baseline: 1.2312x; 1.2312x over previous
//
#include <hip/hip_runtime.h>

#define NN 50000
#define NE 800000
#define C 128
#define OUTC 64
#define BN_EPS 1e-5f
#define INVN (1.0f / 50000.0f)
#define NBLK 49   // ceil(NN/1024)

// ---------------- CSR build ----------------

__global__ __launch_bounds__(256) void hist_kernel(const int* __restrict__ dstp, int* __restrict__ cnt) {
    int e = blockIdx.x * 256 + threadIdx.x;
    if (e < NE) atomicAdd(&cnt[dstp[e]], 1);
}

// phase 1: per-block (1024 elems) local exclusive scan -> rowptr (local), block sum -> bsum; also dinv
__global__ __launch_bounds__(256) void scan1_kernel(const int* __restrict__ cnt, int* __restrict__ rowptr,
                                                    float* __restrict__ dinv, int* __restrict__ bsum) {
    __shared__ int lds[256];
    int tid = threadIdx.x;
    int base = blockIdx.x * 1024 + tid * 4;
    int v[4];
    int s = 0;
    #pragma unroll
    for (int j = 0; j < 4; ++j) { int i = base + j; v[j] = (i < NN) ? cnt[i] : 0; s += v[j]; }
    lds[tid] = s;
    __syncthreads();
    for (int off = 1; off < 256; off <<= 1) {
        int x = (tid >= off) ? lds[tid - off] : 0;
        __syncthreads();
        lds[tid] += x;
        __syncthreads();
    }
    int excl = lds[tid] - s;
    #pragma unroll
    for (int j = 0; j < 4; ++j) {
        int i = base + j;
        if (i < NN) {
            rowptr[i] = excl;                       // local exclusive; offset added in phase 3
            dinv[i] = rsqrtf((float)(v[j] + 1));    // +1 self-loop
        }
        excl += v[j];
    }
    if (tid == 255) bsum[blockIdx.x] = lds[255];
}

// phase 2: one wave scans the 49 block sums in-place (exclusive), writes total
__global__ __launch_bounds__(64) void scan2_kernel(int* __restrict__ bsum, int* __restrict__ rowptr) {
    int tid = threadIdx.x;
    int orig = (tid < NBLK) ? bsum[tid] : 0;
    int v = orig;
    #pragma unroll
    for (int off = 1; off < 64; off <<= 1) {
        int x = __shfl_up(v, off);
        if (tid >= off) v += x;
    }
    if (tid < NBLK) bsum[tid] = v - orig;   // exclusive block offset
    if (tid == 63) rowptr[NN] = v;          // total (= NE)
}

// phase 3: add block offsets, mirror into wpos
__global__ __launch_bounds__(256) void scan3_kernel(const int* __restrict__ bsum, int* __restrict__ rowptr,
                                                    int* __restrict__ wpos) {
    int off = bsum[blockIdx.x];
    int base = blockIdx.x * 1024 + threadIdx.x * 4;
    #pragma unroll
    for (int j = 0; j < 4; ++j) {
        int i = base + j;
        if (i < NN) { int r = rowptr[i] + off; rowptr[i] = r; wpos[i] = r; }
    }
}

__global__ __launch_bounds__(256) void fill_kernel(const int* __restrict__ srcp, const int* __restrict__ dstp,
                                                   int* __restrict__ wpos, int* __restrict__ col) {
    int e = blockIdx.x * 256 + threadIdx.x;
    if (e < NE) {
        int d = dstp[e];
        int p = atomicAdd(&wpos[d], 1);
        col[p] = srcp[e];
    }
}

// Combine Wmu|Wls into one [128][128] and bmu|bls into one [128]
__global__ __launch_bounds__(256) void prep_kernel(const float* __restrict__ Wmu, const float* __restrict__ Wls,
                                                   const float* __restrict__ bmu, const float* __restrict__ bls,
                                                   float* __restrict__ Wcomb, float* __restrict__ biasc) {
    int tid = blockIdx.x * 256 + threadIdx.x;
    if (tid < 128 * 128) {
        int k = tid >> 7, c = tid & 127;
        Wcomb[tid] = (c < 64) ? Wmu[k * 64 + c] : Wls[k * 64 + (c - 64)];
    }
    if (tid < 128) biasc[tid] = (tid < 64) ? bmu[tid] : bls[tid - 64];
}

// ---------------- GEMM: [N x 128] @ [128 x 128], f32 vector ALU ----------------
// TRANS : apply BN(scale/shift from raw sums)+ReLU to A on load
// SPLIT : write cols 0..63 to out (+bias), 64..127 to out2 (+bias), row stride 64
// RSCALE: multiply output row by dinv[row] (pre-scales t for pure-sum aggregation)

template<bool TRANS, bool SPLIT, bool RSCALE>
__global__ __launch_bounds__(256) void gemm_kernel(
    const float* __restrict__ A, const float* __restrict__ W,
    const float* __restrict__ sums, const float* __restrict__ gamma, const float* __restrict__ beta,
    const float* __restrict__ bias, const float* __restrict__ dinv,
    float* __restrict__ out, float* __restrict__ out2)
{
    __shared__ float Ws[64][128];    // 32 KB (one k-half of W)
    __shared__ float xT[128][36];    // 18 KB (transposed 32-row tile, padded)
    int tid = threadIdx.x;
    int row0 = blockIdx.x * 32;

    #pragma unroll
    for (int i = 0; i < 4; ++i) {           // stage 32x128 input tile (float4), transposed
        int idx = tid + i * 256;            // float4 index 0..1023
        int r = idx >> 5;                   // 32 float4 per row
        int k4 = (idx & 31) * 4;
        int gr = row0 + r;
        float vv[4] = {0.f, 0.f, 0.f, 0.f};
        if (gr < NN) {
            float4 v = *(const float4*)&A[(size_t)gr * C + k4];
            vv[0] = v.x; vv[1] = v.y; vv[2] = v.z; vv[3] = v.w;
        }
        if (TRANS) {
            #pragma unroll
            for (int j = 0; j < 4; ++j) {
                int k = k4 + j;
                float mean = sums[k] * INVN;
                float var = fmaf(-mean, mean, sums[128 + k] * INVN);
                float sc = gamma[k] * rsqrtf(var + BN_EPS);
                float sh = fmaf(-mean, sc, beta[k]);
                vv[j] = fmaxf(fmaf(vv[j], sc, sh), 0.f);
            }
        }
        xT[k4 + 0][r] = vv[0]; xT[k4 + 1][r] = vv[1]; xT[k4 + 2][r] = vv[2]; xT[k4 + 3][r] = vv[3];
    }

    float acc[4][4] = {};
    int cg = (tid & 31) * 4;   // output col base
    int rg = (tid >> 5) * 4;   // local row base

    for (int kh = 0; kh < 2; ++kh) {
        __syncthreads();
        #pragma unroll
        for (int i = 0; i < 8; ++i) {       // stage W k-half
            int fi = tid + i * 256;         // float4 index 0..2047
            int k = fi >> 5;
            int c4 = (fi & 31) * 4;
            *(float4*)&Ws[k][c4] = *(const float4*)&W[(kh * 64 + k) * C + c4];
        }
        __syncthreads();
        #pragma unroll 8
        for (int k = 0; k < 64; ++k) {
            float4 a = *(const float4*)&xT[kh * 64 + k][rg];
            float4 b = *(const float4*)&Ws[k][cg];
            acc[0][0] = fmaf(a.x, b.x, acc[0][0]); acc[0][1] = fmaf(a.x, b.y, acc[0][1]);
            acc[0][2] = fmaf(a.x, b.z, acc[0][2]); acc[0][3] = fmaf(a.x, b.w, acc[0][3]);
            acc[1][0] = fmaf(a.y, b.x, acc[1][0]); acc[1][1] = fmaf(a.y, b.y, acc[1][1]);
            acc[1][2] = fmaf(a.y, b.z, acc[1][2]); acc[1][3] = fmaf(a.y, b.w, acc[1][3]);
            acc[2][0] = fmaf(a.z, b.x, acc[2][0]); acc[2][1] = fmaf(a.z, b.y, acc[2][1]);
            acc[2][2] = fmaf(a.z, b.z, acc[2][2]); acc[2][3] = fmaf(a.z, b.w, acc[2][3]);
            acc[3][0] = fmaf(a.w, b.x, acc[3][0]); acc[3][1] = fmaf(a.w, b.y, acc[3][1]);
            acc[3][2] = fmaf(a.w, b.z, acc[3][2]); acc[3][3] = fmaf(a.w, b.w, acc[3][3]);
        }
    }

    #pragma unroll
    for (int i = 0; i < 4; ++i) {
        int row = row0 + rg + i;
        if (row < NN) {
            float rs = RSCALE ? dinv[row] : 1.f;
            if (!SPLIT) {
                float4 o = make_float4(acc[i][0] * rs, acc[i][1] * rs, acc[i][2] * rs, acc[i][3] * rs);
                *(float4*)&out[(size_t)row * C + cg] = o;
            } else {
                float* dst = (cg < 64) ? out : out2;
                int cc = cg & 63;
                float4 o = make_float4(acc[i][0] + bias[cg], acc[i][1] + bias[cg + 1],
                                       acc[i][2] + bias[cg + 2], acc[i][3] + bias[cg + 3]);
                *(float4*)&dst[(size_t)row * 64 + cc] = o;
            }
        }
    }
}

// ---------------- Pull aggregation (pure gather-sum; t rows pre-scaled by dinv) ----------------
// out[i] = dinv[i] * ( t'[i] + sum_{e} t'[col[e]] )      where t' = dinv .* t

__global__ __launch_bounds__(256) void agg_kernel(
    const float* __restrict__ t, const int* __restrict__ rowptr, const int* __restrict__ col,
    const float* __restrict__ dinv, float* __restrict__ outb)
{
    int wave = threadIdx.x >> 6;
    int lane = threadIdx.x & 63;
    int row = blockIdx.x * 4 + wave;
    if (row >= NN) return;
    int c = lane * 2;
    const float* tp = t + c;
    int e0 = rowptr[row], e1 = rowptr[row + 1];
    float a0, a1;
    { float2 v = *(const float2*)&tp[(size_t)row * C]; a0 = v.x; a1 = v.y; }   // self-loop
    int e = e0;
    for (; e + 3 < e1; e += 4) {       // 4 independent gather chains in flight
        int s0 = col[e], s1 = col[e + 1], s2 = col[e + 2], s3 = col[e + 3];
        float2 v0 = *(const float2*)&tp[(size_t)s0 * C];
        float2 v1 = *(const float2*)&tp[(size_t)s1 * C];
        float2 v2 = *(const float2*)&tp[(size_t)s2 * C];
        float2 v3 = *(const float2*)&tp[(size_t)s3 * C];
        a0 += (v0.x + v1.x) + (v2.x + v3.x);
        a1 += (v0.y + v1.y) + (v2.y + v3.y);
    }
    for (; e < e1; ++e) {
        int s = col[e];
        float2 v = *(const float2*)&tp[(size_t)s * C];
        a0 += v.x; a1 += v.y;
    }
    float di = dinv[row];
    *(float2*)&outb[(size_t)row * C + c] = make_float2(di * a0, di * a1);
}

// ---------------- BatchNorm stats ----------------

__global__ __launch_bounds__(256) void bnstats_kernel(const float* __restrict__ h, float* __restrict__ sums) {
    int c = threadIdx.x & 127;
    int hh = threadIdx.x >> 7;
    float s = 0.f, sq = 0.f;
    for (int r = blockIdx.x * 2 + hh; r < NN; r += gridDim.x * 2) {
        float v = h[(size_t)r * C + c];
        s += v; sq = fmaf(v, v, sq);
    }
    __shared__ float ls[256], lq[256];
    ls[threadIdx.x] = s; lq[threadIdx.x] = sq;
    __syncthreads();
    if (hh == 0) {
        atomicAdd(&sums[c], s + ls[c + 128]);
        atomicAdd(&sums[128 + c], sq + lq[c + 128]);
    }
}

// ---------------- layer-3 elementwise: u = dinv .* relu(BN2(aggb)) ----------------

__global__ __launch_bounds__(256) void elem3_kernel(const float* __restrict__ aggb, const float* __restrict__ sums,
                                                    const float* __restrict__ gamma, const float* __restrict__ beta,
                                                    const float* __restrict__ dinv, float* __restrict__ u)
{
    int idx = blockIdx.x * 256 + threadIdx.x;     // float4 index
    const int total = NN * C / 4;
    if (idx >= total) return;
    int row = idx >> 5;                            // 32 float4 per row
    int k4 = (idx & 31) * 4;
    float di = dinv[row];
    float4 v = *(const float4*)&aggb[(size_t)idx * 4];
    float vv[4] = {v.x, v.y, v.z, v.w};
    #pragma unroll
    for (int j = 0; j < 4; ++j) {
        int k = k4 + j;
        float mean = sums[k] * INVN;
        float var = fmaf(-mean, mean, sums[128 + k] * INVN);
        float sc = gamma[k] * rsqrtf(var + BN_EPS);
        float sh = fmaf(-mean, sc, beta[k]);
        vv[j] = di * fmaxf(fmaf(vv[j], sc, sh), 0.f);
    }
    *(float4*)&u[(size_t)idx * 4] = make_float4(vv[0], vv[1], vv[2], vv[3]);
}

// ---------------- launch ----------------

extern "C" void kernel_launch(void* const* d_in, const int* in_sizes, int n_in,
                              void* d_out, int out_size, void* d_ws, size_t ws_size,
                              hipStream_t stream) {
    (void)in_sizes; (void)n_in; (void)out_size; (void)ws_size;
    const float* x      = (const float*)d_in[0];
    const int*   ei     = (const int*)d_in[1];
    const float* W1     = (const float*)d_in[2];
    // d_in[3] = b1: cancelled exactly by BN mean-subtraction
    const float* gamma1 = (const float*)d_in[4];
    const float* beta1  = (const float*)d_in[5];
    const float* W2     = (const float*)d_in[6];
    // d_in[7] = b2: cancelled exactly by BN
    const float* gamma2 = (const float*)d_in[8];
    const float* beta2  = (const float*)d_in[9];
    const float* Wmu    = (const float*)d_in[10];
    const float* bmu    = (const float*)d_in[11];
    const float* Wls    = (const float*)d_in[12];
    const float* bls    = (const float*)d_in[13];

    float* outmu = (float*)d_out;
    float* outls = outmu + (size_t)NN * OUTC;

    char* w = (char*)d_ws;
    size_t off = 0;
    auto alloc = [&](size_t bytes) { char* p = w + off; off = (off + bytes + 255) & ~(size_t)255; return p; };
    float* t      = (float*)alloc(sizeof(float) * NN * C);       // 25.6 MB
    float* aggb   = (float*)alloc(sizeof(float) * NN * C);       // 25.6 MB
    int*   cnt    = (int*)  alloc(sizeof(int) * NN);
    int*   rowptr = (int*)  alloc(sizeof(int) * (NN + 1));
    int*   wpos   = (int*)  alloc(sizeof(int) * NN);
    int*   col    = (int*)  alloc(sizeof(int) * NE);
    float* dinv   = (float*)alloc(sizeof(float) * NN);
    int*   bsum   = (int*)  alloc(sizeof(int) * 64);
    float* sums   = (float*)alloc(sizeof(float) * 512);          // [sumsA(256) | sumsB(256)]
    float* Wcomb  = (float*)alloc(sizeof(float) * C * C);
    float* biasc  = (float*)alloc(512);
    float* sumsA = sums; float* sumsB = sums + 256;

    const int* srcp = ei;
    const int* dstp = ei + NE;

    hipMemsetAsync(cnt, 0, sizeof(int) * NN, stream);
    hipMemsetAsync(sums, 0, sizeof(float) * 512, stream);

    hist_kernel<<<(NE + 255) / 256, 256, 0, stream>>>(dstp, cnt);
    scan1_kernel<<<NBLK, 256, 0, stream>>>(cnt, rowptr, dinv, bsum);
    scan2_kernel<<<1, 64, 0, stream>>>(bsum, rowptr);
    scan3_kernel<<<NBLK, 256, 0, stream>>>(bsum, rowptr, wpos);
    fill_kernel<<<(NE + 255) / 256, 256, 0, stream>>>(srcp, dstp, wpos, col);
    prep_kernel<<<64, 256, 0, stream>>>(Wmu, Wls, bmu, bls, Wcomb, biasc);

    const int GB = (NN + 31) / 32;
    const int AB = (NN + 3) / 4;
    const int EB = (NN * C / 4 + 255) / 256;

    // layer 1: t = dinv .* (x@W1) ; aggb = A_hat-aggregate ; BN1 stats
    gemm_kernel<false, false, true><<<GB, 256, 0, stream>>>(x, W1, nullptr, nullptr, nullptr, nullptr, dinv, t, nullptr);
    agg_kernel<<<AB, 256, 0, stream>>>(t, rowptr, col, dinv, aggb);
    bnstats_kernel<<<400, 256, 0, stream>>>(aggb, sumsA);

    // layer 2: t = dinv .* (relu(BN1(aggb))@W2) ; aggb = aggregate ; BN2 stats
    gemm_kernel<true, false, true><<<GB, 256, 0, stream>>>(aggb, W2, sumsA, gamma1, beta1, nullptr, dinv, t, nullptr);
    agg_kernel<<<AB, 256, 0, stream>>>(t, rowptr, col, dinv, aggb);
    bnstats_kernel<<<400, 256, 0, stream>>>(aggb, sumsB);

    // heads: t = dinv .* relu(BN2(aggb)) ; aggb = aggregate(t) ; [mu|ls] = aggb @ [Wmu|Wls] + bias
    elem3_kernel<<<EB, 256, 0, stream>>>(aggb, sumsB, gamma2, beta2, dinv, t);
    agg_kernel<<<AB, 256, 0, stream>>>(t, rowptr, col, dinv, aggb);
    gemm_kernel<false, true, false><<<GB, 256, 0, stream>>>(aggb, Wcomb, nullptr, nullptr, nullptr, biasc, nullptr, outmu, outls);
}